// Round 10
// baseline (183.661 us; speedup 1.0000x reference)
//
#include <hip/hip_runtime.h>
#include <hip/hip_bf16.h>

#define T_SEQ 2048
#define NBATCH 8
#define EMB 1024
#define HD 128

typedef _Float16 f16_t;
typedef _Float16 f16x8 __attribute__((ext_vector_type(8)));
typedef _Float16 f16x4 __attribute__((ext_vector_type(4)));
typedef float f32x4 __attribute__((ext_vector_type(4)));

// Tiled layouts — every MFMA fragment load is 16B/lane dense:
//  q2/k2 : [tt=row/16][hc=h/8(16)][r16=row%16][8]
//  v2/v2s: [sc=row/8][h(128)][8]
//  w2    : [ntile=n/16(24)][kc8=k/8(128)][r16=n%16][8]
//  e2    : causal-packed per batch (4.125MB):
//          chunk c base = 2048*c*(c+1); tile(t16,s8) at base + (t16&3)*1024*(c+1)
//          + s8*128 + (t%16)*8 + (s%8), valid for s8 < 8*(c+1), c = t16>>2.
// R10: softmax over dim=1 identity: out = E @ (V/colsum) — col_stats now also
// materializes E (exp(S), causal-masked) in PV-A-frag-ready layout; v_scale
// folds 1/colsum into V'; attn_out is pure PV: no QK^T, no exp, no LDS, no
// barriers. Kills the QK^T recompute that cost both attention passes.
// R4 lesson: scattered per-lane A loads -> 8x VMEM; R7: qkv n-split>3 regress.

// async global->LDS, 16B per lane
__device__ __forceinline__ void g2l(const f16_t* g, f16_t* l) {
    __builtin_amdgcn_global_load_lds(
        (const __attribute__((address_space(1))) unsigned int*)g,
        (__attribute__((address_space(3))) unsigned int*)l, 16, 0, 0);
}

// ---------------------------------------------------------------------------
// Kernel 1: prep — w2 pack + scaled biases (zeroing via memset).
// ---------------------------------------------------------------------------
__global__ __launch_bounds__(256) void prep(
    const float* __restrict__ Wk, const float* __restrict__ bk,
    const float* __restrict__ Wq, const float* __restrict__ bq,
    const float* __restrict__ Wv, const float* __restrict__ bv,
    f16_t* __restrict__ w2, float* __restrict__ biasc) {
    int n = blockIdx.x;
    int t = threadIdx.x;
    const float scale = 0.08838834764831845f;  // HEAD^-0.5
    const float* W; const float* bias; float sc; int col;
    if (n < 128)      { W = Wq; bias = bq; sc = scale; col = n; }
    else if (n < 256) { W = Wk; bias = bk; sc = 1.0f;  col = n - 128; }
    else              { W = Wv; bias = bv; sc = 1.0f;  col = n - 256; }
    if (t < 128) {
        int k0 = t * 8;
        f16x8 v;
        #pragma unroll
        for (int i = 0; i < 8; ++i) v[i] = (f16_t)(W[(size_t)(k0 + i) * HD + col] * sc);
        *(f16x8*)&w2[(size_t)(n >> 4) * 16384 + (size_t)(k0 >> 3) * 128 + (n & 15) * 8] = v;
    }
    if (t == 0) biasc[n] = bias[col] * sc;
}

// ---------------------------------------------------------------------------
// Kernel 2: QKV GEMM — EXACT R3 v3 (43.0us verified best).
// ---------------------------------------------------------------------------
__global__ __launch_bounds__(256) void qkv_gemm(
    const float* __restrict__ X, const f16_t* __restrict__ w2,
    const float* __restrict__ biasc,
    f16_t* __restrict__ q2, f16_t* __restrict__ k2, f16_t* __restrict__ v2) {
    __shared__ f16_t Xs[2][64 * 72];
    __shared__ __align__(16) f16_t Bl[2][8 * 1024];

    int bid = blockIdx.x;
    int r8 = bid & 7, g = bid >> 3;
    int band = (g / 3) * 8 + r8;             // 64-row band, XCD-affine
    int i = g % 3;
    int m0 = band * 64, n0 = i * 128;
    int tid = threadIdx.x;
    int lane = tid & 63, w = tid >> 6;
    int quad = lane >> 4, l15 = lane & 15;
    int msub = (w & 1) * 32, nsub = (w >> 1) * 64;

    int srow = tid >> 2;           // 0..63
    int scg  = (tid & 3) * 16;     // 16-float group within BK=64

    const float* xrow = X + (size_t)(m0 + srow) * EMB + scg;
    const f16_t* bbase = w2 + (size_t)(n0 >> 4) * 16384;

    f32x4 acc[2][4] = {};
    float4 pf[4];

    auto loadA = [&](int kc) {
        #pragma unroll
        for (int u = 0; u < 4; ++u) pf[u] = *(const float4*)(xrow + kc * 64 + u * 4);
    };
    auto stageB = [&](int kc, int buf) {
        const f16_t* bsrc = bbase + (size_t)kc * 1024;
        #pragma unroll
        for (int ii = 0; ii < 4; ++ii) {
            int D = tid * 16 + ii * 4096;                 // byte offset in 16KB
            g2l(bsrc + (size_t)(D >> 11) * 16384 + ((D & 2047) >> 1),
                &Bl[buf][D >> 1]);
        }
    };
    auto stageA = [&](int buf) {
        union { f16_t h[8]; uint4 u4; } p0, p1;
        p0.h[0] = (f16_t)pf[0].x; p0.h[1] = (f16_t)pf[0].y;
        p0.h[2] = (f16_t)pf[0].z; p0.h[3] = (f16_t)pf[0].w;
        p0.h[4] = (f16_t)pf[1].x; p0.h[5] = (f16_t)pf[1].y;
        p0.h[6] = (f16_t)pf[1].z; p0.h[7] = (f16_t)pf[1].w;
        p1.h[0] = (f16_t)pf[2].x; p1.h[1] = (f16_t)pf[2].y;
        p1.h[2] = (f16_t)pf[2].z; p1.h[3] = (f16_t)pf[2].w;
        p1.h[4] = (f16_t)pf[3].x; p1.h[5] = (f16_t)pf[3].y;
        p1.h[6] = (f16_t)pf[3].z; p1.h[7] = (f16_t)pf[3].w;
        *(uint4*)&Xs[buf][srow * 72 + scg] = p0.u4;
        *(uint4*)&Xs[buf][srow * 72 + scg + 8] = p1.u4;
    };
    auto compute = [&](int buf) {
        #pragma unroll
        for (int ks = 0; ks < 2; ++ks) {
            f16x8 afr0 = *(const f16x8*)&Xs[buf][(msub + l15) * 72 + ks * 32 + quad * 8];
            f16x8 afr1 = *(const f16x8*)&Xs[buf][(msub + 16 + l15) * 72 + ks * 32 + quad * 8];
            #pragma unroll
            for (int nf = 0; nf < 4; ++nf) {
                int ntl = (nsub >> 4) + nf;
                f16x8 bfr = *(const f16x8*)&Bl[buf][ntl * 1024 + (ks * 4 + quad) * 128 + l15 * 8];
                acc[0][nf] = __builtin_amdgcn_mfma_f32_16x16x32_f16(afr0, bfr, acc[0][nf], 0, 0, 0);
                acc[1][nf] = __builtin_amdgcn_mfma_f32_16x16x32_f16(afr1, bfr, acc[1][nf], 0, 0, 0);
            }
        }
    };

    // prologue: fill buffer 0
    loadA(0);
    stageB(0, 0);
    stageA(0);
    __syncthreads();

    for (int kc = 0; kc < 16; ++kc) {
        int cur = kc & 1, nxt = cur ^ 1;
        if (kc + 1 < 16) {
            loadA(kc + 1);
            stageB(kc + 1, nxt);
        }
        compute(cur);
        if (kc + 1 < 16) stageA(nxt);
        __syncthreads();
    }

    // epilogue -> tiled layouts
    #pragma unroll
    for (int nf = 0; nf < 4; ++nf) {
        int ng = n0 + nsub + nf * 16 + l15;
        float bval = biasc[ng];
        #pragma unroll
        for (int mf = 0; mf < 2; ++mf) {
            int rowg = m0 + msub + mf * 16 + quad * 4;
            f32x4 a = acc[mf][nf];
            if (ng < 256) {
                f16_t* dst = (ng < 128) ? q2 : k2;
                int c = ng & 127;
                #pragma unroll
                for (int r = 0; r < 4; ++r) {
                    int row = rowg + r;
                    dst[(size_t)(row >> 4) * 2048 + (c >> 3) * 128 + (row & 15) * 8 + (c & 7)]
                        = (f16_t)(a[r] + bval);
                }
            } else {
                int h = ng - 256;
                f16x4 hv;
                #pragma unroll
                for (int r = 0; r < 4; ++r) hv[r] = (f16_t)(a[r] + bval);
                *(f16x4*)&v2[(size_t)(rowg >> 3) * 1024 + h * 8 + (rowg & 7)] = hv;
            }
        }
    }
}

// ---------------------------------------------------------------------------
// Kernel 3: column sums + E materialization. Barrier-free (R4 v2 base).
// E stored causal-packed in PV-A-frag-ready layout; masked entries = 0.
// ---------------------------------------------------------------------------
__global__ __launch_bounds__(256, 4) void col_stats(
    const f16_t* __restrict__ q2, const f16_t* __restrict__ k2,
    float* __restrict__ colsum, f16_t* __restrict__ e2) {
    int bid = blockIdx.x;
    int b = bid & 7;
    int item = 143 - (bid >> 3);
    int cg = 0, slab = 0, cum = 0;
    for (int c = 0; c < 32; ++c) {
        int n = (32 - c + 3) >> 2;
        if (item < cum + n) { cg = c; slab = item - cum; break; }
        cum += n;
    }
    int tc0 = cg + slab * 4, tc1 = min(tc0 + 4, 32);

    int tid = threadIdx.x, lane = tid & 63, w = tid >> 6;
    int quad = lane >> 4, l15 = lane & 15;
    int brow = b * 128;
    size_t base = (size_t)b * T_SEQ;
    size_t ebb = (size_t)b * 2162688;

    f16x8 bfrs[4][4];
    #pragma unroll
    for (int st = 0; st < 4; ++st) {
        const f16_t* kt = k2 + (size_t)(brow + cg * 4 + st) * 2048 + l15 * 8;
        #pragma unroll
        for (int kf = 0; kf < 4; ++kf)
            bfrs[st][kf] = *(const f16x8*)(kt + (kf * 4 + quad) * 128);
    }

    float lacc[4] = {0.f, 0.f, 0.f, 0.f};

    for (int tc = tc0; tc < tc1; ++tc) {
        int tb = tc * 64;
        size_t ebase = ebb + (size_t)2048 * tc * (tc + 1) + (size_t)w * 1024 * (tc + 1);
        f16x8 afr[4];
        const f16_t* qt = q2 + (size_t)(brow + tc * 4 + w) * 2048 + l15 * 8;
        #pragma unroll
        for (int kf = 0; kf < 4; ++kf)
            afr[kf] = *(const f16x8*)(qt + (kf * 4 + quad) * 128);
        #pragma unroll
        for (int st = 0; st < 4; ++st) {
            f32x4 s = {};
            #pragma unroll
            for (int kf = 0; kf < 4; ++kf)
                s = __builtin_amdgcn_mfma_f32_16x16x32_f16(afr[kf], bfrs[st][kf], s, 0, 0, 0);
            int scol = cg * 64 + st * 16 + l15;
            int s8 = cg * 8 + st * 2 + (l15 >> 3);
            f16_t* ep = e2 + ebase + (size_t)s8 * 128 + (l15 & 7);
            #pragma unroll
            for (int r = 0; r < 4; ++r) {
                int t = tb + w * 16 + quad * 4 + r;
                float e = __expf(s[r]);
                float ev = (t >= scol) ? e : 0.f;
                lacc[st] += ev;
                ep[(quad * 4 + r) * 8] = (f16_t)ev;
            }
        }
    }

    #pragma unroll
    for (int st = 0; st < 4; ++st) {
        float v = lacc[st];
        v += __shfl_xor(v, 16, 64);
        v += __shfl_xor(v, 32, 64);
        if (quad == 0) atomicAdd(&colsum[base + cg * 64 + st * 16 + l15], v);
    }
}

// ---------------------------------------------------------------------------
// Kernel 3b: fold 1/colsum into V: v2s = v2 / colsum[row]. 1024 blocks.
// ---------------------------------------------------------------------------
__global__ __launch_bounds__(256) void v_scale(
    const f16_t* __restrict__ v2, const float* __restrict__ colsum,
    f16_t* __restrict__ v2s) {
    int i = blockIdx.x * 256 + threadIdx.x;        // 262144 threads
    size_t o = (size_t)i * 8;
    int rg = (int)(o >> 10);                       // row-group of 8
    f16x8 v = *(const f16x8*)&v2[o];
    float4 c0 = *(const float4*)&colsum[rg * 8];
    float4 c1 = *(const float4*)&colsum[rg * 8 + 4];
    f16x8 r;
    r[0] = (f16_t)((float)v[0] / c0.x); r[1] = (f16_t)((float)v[1] / c0.y);
    r[2] = (f16_t)((float)v[2] / c0.z); r[3] = (f16_t)((float)v[3] / c0.w);
    r[4] = (f16_t)((float)v[4] / c1.x); r[5] = (f16_t)((float)v[5] / c1.y);
    r[6] = (f16_t)((float)v[6] / c1.z); r[7] = (f16_t)((float)v[7] / c1.w);
    *(f16x8*)&v2s[o] = r;
}

// ---------------------------------------------------------------------------
// Kernel 4 (v5): pure PV. out[t] = sum_s E[t,s] * V'[s]. No QK^T, no exp,
// no LDS, no barriers — per chunk: 8x16B loads + 8 MFMA. Waves independent.
// ---------------------------------------------------------------------------
__global__ __launch_bounds__(256, 4) void attn_out(
    const f16_t* __restrict__ e2, const f16_t* __restrict__ v2s,
    float* __restrict__ out) {
    int bid = blockIdx.x;
    int b = bid & 7;
    int item = 159 - (bid >> 3);
    int g = 0, slab = 0, cum = 0;
    for (int gg = 0; gg < 64; ++gg) {
        int n = (((gg >> 1) + 1) + 7) >> 3;
        if (item < cum + n) { g = gg; slab = item - cum; break; }
        cum += n;
    }
    int nch = (g >> 1) + 1;
    int c0 = slab * 8, c1 = min(c0 + 8, nch);
    int trow = g * 32;

    int tid = threadIdx.x, lane = tid & 63, w = tid >> 6;
    int quad = lane >> 4, l15 = lane & 15;
    size_t base = (size_t)b * T_SEQ;

    int ct = g >> 1;
    size_t et1 = (size_t)1024 * (ct + 1);          // tile stride within chunk
    size_t eb = (size_t)b * 2162688 + (size_t)2048 * ct * (ct + 1)
              + (size_t)((2 * g) & 3) * et1;

    f32x4 o[2][2] = {};

    for (int c = c0; c < c1; ++c) {
        f16x8 pa[2][2], vf[2][2];
        const f16_t* vt = v2s + ((size_t)(base + c * 64) >> 3) * 1024;
        #pragma unroll
        for (int kf2 = 0; kf2 < 2; ++kf2) {
            size_t es = eb + (size_t)(c * 8 + kf2 * 4 + quad) * 128 + l15 * 8;
            pa[0][kf2] = *(const f16x8*)&e2[es];
            pa[1][kf2] = *(const f16x8*)&e2[es + et1];
            #pragma unroll
            for (int hh = 0; hh < 2; ++hh)
                vf[kf2][hh] = *(const f16x8*)&vt[(kf2 * 4 + quad) * 1024 +
                                                 (w * 32 + hh * 16 + l15) * 8];
        }
        #pragma unroll
        for (int kf2 = 0; kf2 < 2; ++kf2)
            #pragma unroll
            for (int hh = 0; hh < 2; ++hh) {
                o[0][hh] = __builtin_amdgcn_mfma_f32_16x16x32_f16(pa[0][kf2], vf[kf2][hh], o[0][hh], 0, 0, 0);
                o[1][hh] = __builtin_amdgcn_mfma_f32_16x16x32_f16(pa[1][kf2], vf[kf2][hh], o[1][hh], 0, 0, 0);
            }
    }

    #pragma unroll
    for (int tt = 0; tt < 2; ++tt)
        #pragma unroll
        for (int hh = 0; hh < 2; ++hh)
            #pragma unroll
            for (int r = 0; r < 4; ++r)
                atomicAdd(&out[(base + trow + tt * 16 + quad * 4 + r) * HD + w * 32 + hh * 16 + l15],
                          o[tt][hh][r]);
}

// ---------------------------------------------------------------------------
extern "C" void kernel_launch(void* const* d_in, const int* in_sizes, int n_in,
                              void* d_out, int out_size, void* d_ws, size_t ws_size,
                              hipStream_t stream) {
    const float* X  = (const float*)d_in[0];
    const float* Wk = (const float*)d_in[1];
    const float* bk = (const float*)d_in[2];
    const float* Wq = (const float*)d_in[3];
    const float* bq = (const float*)d_in[4];
    const float* Wv = (const float*)d_in[5];
    const float* bv = (const float*)d_in[6];
    float* out = (float*)d_out;

    char* ws = (char*)d_ws;
    const size_t W2_B    = 24 * 16384 * 2;                   // 768 KiB
    const size_t BIAS_B  = 2048;
    const size_t QKV_B   = (size_t)NBATCH * T_SEQ * HD * 2;  // 4 MiB each
    const size_t CS_B    = (size_t)NBATCH * T_SEQ * 4;       // 64 KiB
    f16_t* w2     = (f16_t*)ws;
    float* biasc  = (float*)(ws + W2_B);
    f16_t* q2     = (f16_t*)(ws + W2_B + BIAS_B);
    f16_t* k2     = (f16_t*)(ws + W2_B + BIAS_B + QKV_B);
    f16_t* v2     = (f16_t*)(ws + W2_B + BIAS_B + 2 * QKV_B);
    float* colsum = (float*)(ws + W2_B + BIAS_B + 3 * QKV_B);
    f16_t* v2s    = (f16_t*)(ws + W2_B + BIAS_B + 3 * QKV_B + CS_B);
    f16_t* e2     = (f16_t*)(ws + W2_B + BIAS_B + 4 * QKV_B + CS_B);
    // e2 size: 8 batches x 2,162,688 f16 = 34.6 MB; total ws ~52.2 MB.

    hipMemsetAsync(out, 0, (size_t)NBATCH * T_SEQ * HD * sizeof(float), stream);
    hipMemsetAsync(colsum, 0, CS_B, stream);

    prep<<<dim3(384), dim3(256), 0, stream>>>(Wk, bk, Wq, bq, Wv, bv, w2, biasc);
    qkv_gemm<<<dim3(768), dim3(256), 0, stream>>>(X, w2, biasc, q2, k2, v2);
    col_stats<<<dim3(1152), dim3(256), 0, stream>>>(q2, k2, colsum, e2);
    v_scale<<<dim3(1024), dim3(256), 0, stream>>>(v2, colsum, v2s);
    attn_out<<<dim3(1280), dim3(256), 0, stream>>>(e2, v2s, out);
}

// Round 11
// 178.372 us; speedup vs baseline: 1.0297x; 1.0297x over previous
//
#include <hip/hip_runtime.h>
#include <hip/hip_bf16.h>

#define T_SEQ 2048
#define NBATCH 8
#define EMB 1024
#define HD 128

typedef _Float16 f16_t;
typedef _Float16 f16x8 __attribute__((ext_vector_type(8)));
typedef _Float16 f16x4 __attribute__((ext_vector_type(4)));
typedef float f32x4 __attribute__((ext_vector_type(4)));

// Tiled layouts — every MFMA fragment load is 16B/lane dense:
//  q2/k2 : [tt=row/16][hc=h/8(16)][r16=row%16][8]
//  v2/v2s: [sc=row/8][h(128)][8]
//  w2    : [ntile=n/16(24)][kc8=k/8(128)][r16=n%16][8]
//  e2    : causal-packed per batch (4.125MB):
//          chunk c base = 2048*c*(c+1); tile(t16,s8) at base + (t16&3)*1024*(c+1)
//          + s8*128 + (t%16)*8 + (s%8), valid for s8 < 8*(c+1), c = t16>>2.
// R10: out = E @ (V/colsum) factorization (softmax over dim=1). Verified.
// R11: col_stats E-store fixed — R10 used 16 scalar 2B stores/lane/tile
// (transaction storm, R4 lesson on the store side). Now: wave-private LDS
// transpose slab [16][72] (padded, no barriers, wave-local lgkmcnt only),
// then 2x dense 16B global stores per lane (1KB/instr). e2 bytes identical.

// async global->LDS, 16B per lane
__device__ __forceinline__ void g2l(const f16_t* g, f16_t* l) {
    __builtin_amdgcn_global_load_lds(
        (const __attribute__((address_space(1))) unsigned int*)g,
        (__attribute__((address_space(3))) unsigned int*)l, 16, 0, 0);
}

// ---------------------------------------------------------------------------
// Kernel 1: prep — w2 pack + scaled biases (zeroing via memset).
// ---------------------------------------------------------------------------
__global__ __launch_bounds__(256) void prep(
    const float* __restrict__ Wk, const float* __restrict__ bk,
    const float* __restrict__ Wq, const float* __restrict__ bq,
    const float* __restrict__ Wv, const float* __restrict__ bv,
    f16_t* __restrict__ w2, float* __restrict__ biasc) {
    int n = blockIdx.x;
    int t = threadIdx.x;
    const float scale = 0.08838834764831845f;  // HEAD^-0.5
    const float* W; const float* bias; float sc; int col;
    if (n < 128)      { W = Wq; bias = bq; sc = scale; col = n; }
    else if (n < 256) { W = Wk; bias = bk; sc = 1.0f;  col = n - 128; }
    else              { W = Wv; bias = bv; sc = 1.0f;  col = n - 256; }
    if (t < 128) {
        int k0 = t * 8;
        f16x8 v;
        #pragma unroll
        for (int i = 0; i < 8; ++i) v[i] = (f16_t)(W[(size_t)(k0 + i) * HD + col] * sc);
        *(f16x8*)&w2[(size_t)(n >> 4) * 16384 + (size_t)(k0 >> 3) * 128 + (n & 15) * 8] = v;
    }
    if (t == 0) biasc[n] = bias[col] * sc;
}

// ---------------------------------------------------------------------------
// Kernel 2: QKV GEMM — EXACT R3 v3 (43.0us verified best).
// ---------------------------------------------------------------------------
__global__ __launch_bounds__(256) void qkv_gemm(
    const float* __restrict__ X, const f16_t* __restrict__ w2,
    const float* __restrict__ biasc,
    f16_t* __restrict__ q2, f16_t* __restrict__ k2, f16_t* __restrict__ v2) {
    __shared__ f16_t Xs[2][64 * 72];
    __shared__ __align__(16) f16_t Bl[2][8 * 1024];

    int bid = blockIdx.x;
    int r8 = bid & 7, g = bid >> 3;
    int band = (g / 3) * 8 + r8;             // 64-row band, XCD-affine
    int i = g % 3;
    int m0 = band * 64, n0 = i * 128;
    int tid = threadIdx.x;
    int lane = tid & 63, w = tid >> 6;
    int quad = lane >> 4, l15 = lane & 15;
    int msub = (w & 1) * 32, nsub = (w >> 1) * 64;

    int srow = tid >> 2;           // 0..63
    int scg  = (tid & 3) * 16;     // 16-float group within BK=64

    const float* xrow = X + (size_t)(m0 + srow) * EMB + scg;
    const f16_t* bbase = w2 + (size_t)(n0 >> 4) * 16384;

    f32x4 acc[2][4] = {};
    float4 pf[4];

    auto loadA = [&](int kc) {
        #pragma unroll
        for (int u = 0; u < 4; ++u) pf[u] = *(const float4*)(xrow + kc * 64 + u * 4);
    };
    auto stageB = [&](int kc, int buf) {
        const f16_t* bsrc = bbase + (size_t)kc * 1024;
        #pragma unroll
        for (int ii = 0; ii < 4; ++ii) {
            int D = tid * 16 + ii * 4096;                 // byte offset in 16KB
            g2l(bsrc + (size_t)(D >> 11) * 16384 + ((D & 2047) >> 1),
                &Bl[buf][D >> 1]);
        }
    };
    auto stageA = [&](int buf) {
        union { f16_t h[8]; uint4 u4; } p0, p1;
        p0.h[0] = (f16_t)pf[0].x; p0.h[1] = (f16_t)pf[0].y;
        p0.h[2] = (f16_t)pf[0].z; p0.h[3] = (f16_t)pf[0].w;
        p0.h[4] = (f16_t)pf[1].x; p0.h[5] = (f16_t)pf[1].y;
        p0.h[6] = (f16_t)pf[1].z; p0.h[7] = (f16_t)pf[1].w;
        p1.h[0] = (f16_t)pf[2].x; p1.h[1] = (f16_t)pf[2].y;
        p1.h[2] = (f16_t)pf[2].z; p1.h[3] = (f16_t)pf[2].w;
        p1.h[4] = (f16_t)pf[3].x; p1.h[5] = (f16_t)pf[3].y;
        p1.h[6] = (f16_t)pf[3].z; p1.h[7] = (f16_t)pf[3].w;
        *(uint4*)&Xs[buf][srow * 72 + scg] = p0.u4;
        *(uint4*)&Xs[buf][srow * 72 + scg + 8] = p1.u4;
    };
    auto compute = [&](int buf) {
        #pragma unroll
        for (int ks = 0; ks < 2; ++ks) {
            f16x8 afr0 = *(const f16x8*)&Xs[buf][(msub + l15) * 72 + ks * 32 + quad * 8];
            f16x8 afr1 = *(const f16x8*)&Xs[buf][(msub + 16 + l15) * 72 + ks * 32 + quad * 8];
            #pragma unroll
            for (int nf = 0; nf < 4; ++nf) {
                int ntl = (nsub >> 4) + nf;
                f16x8 bfr = *(const f16x8*)&Bl[buf][ntl * 1024 + (ks * 4 + quad) * 128 + l15 * 8];
                acc[0][nf] = __builtin_amdgcn_mfma_f32_16x16x32_f16(afr0, bfr, acc[0][nf], 0, 0, 0);
                acc[1][nf] = __builtin_amdgcn_mfma_f32_16x16x32_f16(afr1, bfr, acc[1][nf], 0, 0, 0);
            }
        }
    };

    // prologue: fill buffer 0
    loadA(0);
    stageB(0, 0);
    stageA(0);
    __syncthreads();

    for (int kc = 0; kc < 16; ++kc) {
        int cur = kc & 1, nxt = cur ^ 1;
        if (kc + 1 < 16) {
            loadA(kc + 1);
            stageB(kc + 1, nxt);
        }
        compute(cur);
        if (kc + 1 < 16) stageA(nxt);
        __syncthreads();
    }

    // epilogue -> tiled layouts
    #pragma unroll
    for (int nf = 0; nf < 4; ++nf) {
        int ng = n0 + nsub + nf * 16 + l15;
        float bval = biasc[ng];
        #pragma unroll
        for (int mf = 0; mf < 2; ++mf) {
            int rowg = m0 + msub + mf * 16 + quad * 4;
            f32x4 a = acc[mf][nf];
            if (ng < 256) {
                f16_t* dst = (ng < 128) ? q2 : k2;
                int c = ng & 127;
                #pragma unroll
                for (int r = 0; r < 4; ++r) {
                    int row = rowg + r;
                    dst[(size_t)(row >> 4) * 2048 + (c >> 3) * 128 + (row & 15) * 8 + (c & 7)]
                        = (f16_t)(a[r] + bval);
                }
            } else {
                int h = ng - 256;
                f16x4 hv;
                #pragma unroll
                for (int r = 0; r < 4; ++r) hv[r] = (f16_t)(a[r] + bval);
                *(f16x4*)&v2[(size_t)(rowg >> 3) * 1024 + h * 8 + (rowg & 7)] = hv;
            }
        }
    }
}

// ---------------------------------------------------------------------------
// Kernel 3: column sums + E materialization (v2). Barrier-free. E goes
// through a wave-private LDS transpose slab, then dense 16B global stores.
// e2 layout byte-identical to R10 (verified).
// ---------------------------------------------------------------------------
__global__ __launch_bounds__(256, 4) void col_stats(
    const f16_t* __restrict__ q2, const f16_t* __restrict__ k2,
    float* __restrict__ colsum, f16_t* __restrict__ e2) {
    __shared__ __align__(16) f16_t El[4 * 1152];   // 4 waves x [16][72]

    int bid = blockIdx.x;
    int b = bid & 7;
    int item = 143 - (bid >> 3);
    int cg = 0, slab = 0, cum = 0;
    for (int c = 0; c < 32; ++c) {
        int n = (32 - c + 3) >> 2;
        if (item < cum + n) { cg = c; slab = item - cum; break; }
        cum += n;
    }
    int tc0 = cg + slab * 4, tc1 = min(tc0 + 4, 32);

    int tid = threadIdx.x, lane = tid & 63, w = tid >> 6;
    int quad = lane >> 4, l15 = lane & 15;
    int brow = b * 128;
    size_t base = (size_t)b * T_SEQ;
    size_t ebb = (size_t)b * 2162688;

    f16x8 bfrs[4][4];
    #pragma unroll
    for (int st = 0; st < 4; ++st) {
        const f16_t* kt = k2 + (size_t)(brow + cg * 4 + st) * 2048 + l15 * 8;
        #pragma unroll
        for (int kf = 0; kf < 4; ++kf)
            bfrs[st][kf] = *(const f16x8*)(kt + (kf * 4 + quad) * 128);
    }

    float lacc[4] = {0.f, 0.f, 0.f, 0.f};
    f16_t* sl = El + w * 1152;

    for (int tc = tc0; tc < tc1; ++tc) {
        int tb = tc * 64;
        f16x8 afr[4];
        const f16_t* qt = q2 + (size_t)(brow + tc * 4 + w) * 2048 + l15 * 8;
        #pragma unroll
        for (int kf = 0; kf < 4; ++kf)
            afr[kf] = *(const f16x8*)(qt + (kf * 4 + quad) * 128);
        #pragma unroll
        for (int st = 0; st < 4; ++st) {
            f32x4 s = {};
            #pragma unroll
            for (int kf = 0; kf < 4; ++kf)
                s = __builtin_amdgcn_mfma_f32_16x16x32_f16(afr[kf], bfrs[st][kf], s, 0, 0, 0);
            int scol = cg * 64 + st * 16 + l15;
            #pragma unroll
            for (int r = 0; r < 4; ++r) {
                int t = tb + w * 16 + quad * 4 + r;
                float e = __expf(s[r]);
                float ev = (t >= scol) ? e : 0.f;
                lacc[st] += ev;
                // LDS slab [t%16][s_local], row stride 72 (pad -> <=4-way)
                sl[(quad * 4 + r) * 72 + st * 16 + l15] = (f16_t)ev;
            }
        }
        // copy-out: wave's 2KB e2 region, dense 16B stores (1KB/instr)
        size_t ebase = ebb + (size_t)2048 * tc * (tc + 1)
                     + (size_t)w * 1024 * (tc + 1) + (size_t)cg * 1024;
        #pragma unroll
        for (int half = 0; half < 2; ++half) {
            int c = half * 64 + lane;          // chunk 0..127, 8 f16 each
            f16x8 v = *(const f16x8*)&sl[(c & 15) * 72 + (c >> 4) * 8];
            *(f16x8*)&e2[ebase + (size_t)c * 8] = v;
        }
    }

    #pragma unroll
    for (int st = 0; st < 4; ++st) {
        float v = lacc[st];
        v += __shfl_xor(v, 16, 64);
        v += __shfl_xor(v, 32, 64);
        if (quad == 0) atomicAdd(&colsum[base + cg * 64 + st * 16 + l15], v);
    }
}

// ---------------------------------------------------------------------------
// Kernel 3b: fold 1/colsum into V: v2s = v2 / colsum[row]. Verified R10.
// ---------------------------------------------------------------------------
__global__ __launch_bounds__(256) void v_scale(
    const f16_t* __restrict__ v2, const float* __restrict__ colsum,
    f16_t* __restrict__ v2s) {
    int i = blockIdx.x * 256 + threadIdx.x;        // 262144 threads
    size_t o = (size_t)i * 8;
    int rg = (int)(o >> 10);                       // row-group of 8
    f16x8 v = *(const f16x8*)&v2[o];
    float4 c0 = *(const float4*)&colsum[rg * 8];
    float4 c1 = *(const float4*)&colsum[rg * 8 + 4];
    f16x8 r;
    r[0] = (f16_t)((float)v[0] / c0.x); r[1] = (f16_t)((float)v[1] / c0.y);
    r[2] = (f16_t)((float)v[2] / c0.z); r[3] = (f16_t)((float)v[3] / c0.w);
    r[4] = (f16_t)((float)v[4] / c1.x); r[5] = (f16_t)((float)v[5] / c1.y);
    r[6] = (f16_t)((float)v[6] / c1.z); r[7] = (f16_t)((float)v[7] / c1.w);
    *(f16x8*)&v2s[o] = r;
}

// ---------------------------------------------------------------------------
// Kernel 4 (v5): pure PV. out[t] = sum_s E[t,s] * V'[s]. Verified R10.
// No QK^T, no exp, no LDS, no barriers.
// ---------------------------------------------------------------------------
__global__ __launch_bounds__(256, 4) void attn_out(
    const f16_t* __restrict__ e2, const f16_t* __restrict__ v2s,
    float* __restrict__ out) {
    int bid = blockIdx.x;
    int b = bid & 7;
    int item = 159 - (bid >> 3);
    int g = 0, slab = 0, cum = 0;
    for (int gg = 0; gg < 64; ++gg) {
        int n = (((gg >> 1) + 1) + 7) >> 3;
        if (item < cum + n) { g = gg; slab = item - cum; break; }
        cum += n;
    }
    int nch = (g >> 1) + 1;
    int c0 = slab * 8, c1 = min(c0 + 8, nch);
    int trow = g * 32;

    int tid = threadIdx.x, lane = tid & 63, w = tid >> 6;
    int quad = lane >> 4, l15 = lane & 15;
    size_t base = (size_t)b * T_SEQ;

    int ct = g >> 1;
    size_t et1 = (size_t)1024 * (ct + 1);          // tile stride within chunk
    size_t eb = (size_t)b * 2162688 + (size_t)2048 * ct * (ct + 1)
              + (size_t)((2 * g) & 3) * et1;

    f32x4 o[2][2] = {};

    for (int c = c0; c < c1; ++c) {
        f16x8 pa[2][2], vf[2][2];
        const f16_t* vt = v2s + ((size_t)(base + c * 64) >> 3) * 1024;
        #pragma unroll
        for (int kf2 = 0; kf2 < 2; ++kf2) {
            size_t es = eb + (size_t)(c * 8 + kf2 * 4 + quad) * 128 + l15 * 8;
            pa[0][kf2] = *(const f16x8*)&e2[es];
            pa[1][kf2] = *(const f16x8*)&e2[es + et1];
            #pragma unroll
            for (int hh = 0; hh < 2; ++hh)
                vf[kf2][hh] = *(const f16x8*)&vt[(kf2 * 4 + quad) * 1024 +
                                                 (w * 32 + hh * 16 + l15) * 8];
        }
        #pragma unroll
        for (int kf2 = 0; kf2 < 2; ++kf2)
            #pragma unroll
            for (int hh = 0; hh < 2; ++hh) {
                o[0][hh] = __builtin_amdgcn_mfma_f32_16x16x32_f16(pa[0][kf2], vf[kf2][hh], o[0][hh], 0, 0, 0);
                o[1][hh] = __builtin_amdgcn_mfma_f32_16x16x32_f16(pa[1][kf2], vf[kf2][hh], o[1][hh], 0, 0, 0);
            }
    }

    #pragma unroll
    for (int tt = 0; tt < 2; ++tt)
        #pragma unroll
        for (int hh = 0; hh < 2; ++hh)
            #pragma unroll
            for (int r = 0; r < 4; ++r)
                atomicAdd(&out[(base + trow + tt * 16 + quad * 4 + r) * HD + w * 32 + hh * 16 + l15],
                          o[tt][hh][r]);
}

// ---------------------------------------------------------------------------
extern "C" void kernel_launch(void* const* d_in, const int* in_sizes, int n_in,
                              void* d_out, int out_size, void* d_ws, size_t ws_size,
                              hipStream_t stream) {
    const float* X  = (const float*)d_in[0];
    const float* Wk = (const float*)d_in[1];
    const float* bk = (const float*)d_in[2];
    const float* Wq = (const float*)d_in[3];
    const float* bq = (const float*)d_in[4];
    const float* Wv = (const float*)d_in[5];
    const float* bv = (const float*)d_in[6];
    float* out = (float*)d_out;

    char* ws = (char*)d_ws;
    const size_t W2_B    = 24 * 16384 * 2;                   // 768 KiB
    const size_t BIAS_B  = 2048;
    const size_t QKV_B   = (size_t)NBATCH * T_SEQ * HD * 2;  // 4 MiB each
    const size_t CS_B    = (size_t)NBATCH * T_SEQ * 4;       // 64 KiB
    f16_t* w2     = (f16_t*)ws;
    float* biasc  = (float*)(ws + W2_B);
    f16_t* q2     = (f16_t*)(ws + W2_B + BIAS_B);
    f16_t* k2     = (f16_t*)(ws + W2_B + BIAS_B + QKV_B);
    f16_t* v2     = (f16_t*)(ws + W2_B + BIAS_B + 2 * QKV_B);
    float* colsum = (float*)(ws + W2_B + BIAS_B + 3 * QKV_B);
    f16_t* v2s    = (f16_t*)(ws + W2_B + BIAS_B + 3 * QKV_B + CS_B);
    f16_t* e2     = (f16_t*)(ws + W2_B + BIAS_B + 4 * QKV_B + CS_B);
    // e2 size: 8 batches x 2,162,688 f16 = 34.6 MB; total ws ~52.2 MB.

    hipMemsetAsync(out, 0, (size_t)NBATCH * T_SEQ * HD * sizeof(float), stream);
    hipMemsetAsync(colsum, 0, CS_B, stream);

    prep<<<dim3(384), dim3(256), 0, stream>>>(Wk, bk, Wq, bq, Wv, bv, w2, biasc);
    qkv_gemm<<<dim3(768), dim3(256), 0, stream>>>(X, w2, biasc, q2, k2, v2);
    col_stats<<<dim3(1152), dim3(256), 0, stream>>>(q2, k2, colsum, e2);
    v_scale<<<dim3(1024), dim3(256), 0, stream>>>(v2, colsum, v2s);
    attn_out<<<dim3(1280), dim3(256), 0, stream>>>(e2, v2s, out);
}